// Round 2
// baseline (274.257 us; speedup 1.0000x reference)
//
#include <hip/hip_runtime.h>
#include <stdint.h>

#define TOKENS 8192
#define EDIM 512
#define HNUM 8
#define RNUM 16
#define DDIM 64
#define KDIM 512

typedef short v8s __attribute__((ext_vector_type(8)));
typedef float v4f __attribute__((ext_vector_type(4)));

__device__ inline unsigned short f2b(float f) {
    union { float f; unsigned int i; } c; c.f = f;
    unsigned int i = c.i + 0x7fffu + ((c.i >> 16) & 1u);
    return (unsigned short)(i >> 16);
}

// async global->LDS, 16B per lane; LDS dest = wave-uniform base + lane*16
#define GLD16(dst, src) \
    __builtin_amdgcn_global_load_lds((__attribute__((address_space(1))) void*)(src), \
                                     (__attribute__((address_space(3))) void*)(dst), 16, 0, 0)

// ---- fp32 -> bf16 convert, 5 segments in one launch (blockIdx.y picks) ----
__global__ __launch_bounds__(256)
void cvt5(const float* __restrict__ s0, const float* __restrict__ s1,
          const float* __restrict__ s2, const float* __restrict__ s3,
          const float* __restrict__ s4,
          unsigned short* __restrict__ d0, unsigned short* __restrict__ d1,
          unsigned short* __restrict__ d2, unsigned short* __restrict__ d3,
          unsigned short* __restrict__ d4,
          int n0, int n1, int n2, int n3, int n4)
{
    const float* s; unsigned short* d; int n;
    switch (blockIdx.y) {
        case 0: s = s0; d = d0; n = n0; break;
        case 1: s = s1; d = d1; n = n1; break;
        case 2: s = s2; d = d2; n = n2; break;
        case 3: s = s3; d = d3; n = n3; break;
        default: s = s4; d = d4; n = n4; break;
    }
    size_t base = (size_t)blockIdx.x * 2048 + (size_t)threadIdx.x * 8;
    if (base >= (size_t)n) return;
    const float4* sp = (const float4*)(s + base);
    float4 f0 = sp[0], f1 = sp[1];
    v8s o;
    o[0] = (short)f2b(f0.x); o[1] = (short)f2b(f0.y);
    o[2] = (short)f2b(f0.z); o[3] = (short)f2b(f0.w);
    o[4] = (short)f2b(f1.x); o[5] = (short)f2b(f1.y);
    o[6] = (short)f2b(f1.z); o[7] = (short)f2b(f1.w);
    *(v8s*)(d + base) = o;
}

// C[m,n] = sum_k A[m,k]*B[n,k]   (A: M x 512 bf16 row-major, B: N x 512 bf16 row-major)
// MODE 0: outF[m*512+n] = (C + bias[n]) * 0.125          (Q projection, fp32 out)
// MODE 1: rule-contract epilogue -> scrambled-layout bf16 out1
// MODE 2: outF[m*512+n] = C + bias[n]                    (O projection, fp32 out)
template <int MODE>
__global__ __launch_bounds__(256, 2)
void gemm_bt(const unsigned short* __restrict__ A,
             const unsigned short* __restrict__ B,
             const float* __restrict__ bias,
             float* __restrict__ outF,
             unsigned short* __restrict__ outH,
             const float* __restrict__ attn)
{
    __shared__ unsigned short As[128 * 32];
    __shared__ unsigned short Bs[128 * 32];

    const int tid  = threadIdx.x;
    const int w    = tid >> 6;
    const int lane = tid & 63;
    const int quad = lane >> 4;
    const int l16  = lane & 15;
    const int wm   = w >> 1, wn = w & 1;
    const int m0   = blockIdx.x * 128;
    const int n0   = blockIdx.y * 128;

    v4f acc[4][4];
#pragma unroll
    for (int i = 0; i < 4; ++i)
#pragma unroll
        for (int j = 0; j < 4; ++j)
            acc[i][j] = (v4f){0.f, 0.f, 0.f, 0.f};

    for (int kt = 0; kt < KDIM / 32; ++kt) {
        // ---- stage A,B tiles (128x32 bf16 each) via global_load_lds ----
#pragma unroll
        for (int p = 0; p < 2; ++p) {
            int cb = w * 128 + p * 64;     // wave-uniform chunk base (16B chunks)
            int c  = cb + lane;            // this lane's chunk
            const unsigned short* sa = A + (size_t)(m0 + (c >> 2)) * KDIM + kt * 32 + (c & 3) * 8;
            GLD16(&As[cb * 8], sa);
            const unsigned short* sb = B + (size_t)(n0 + (c >> 2)) * KDIM + kt * 32 + (c & 3) * 8;
            GLD16(&Bs[cb * 8], sb);
        }
        __syncthreads();

        // ---- fragments + 16 MFMAs ----
        v8s af[4], bf[4];
#pragma unroll
        for (int mt = 0; mt < 4; ++mt)
            af[mt] = *(const v8s*)&As[(wm * 64 + mt * 16 + l16) * 32 + quad * 8];
#pragma unroll
        for (int nt = 0; nt < 4; ++nt)
            bf[nt] = *(const v8s*)&Bs[(wn * 64 + nt * 16 + l16) * 32 + quad * 8];
#pragma unroll
        for (int mt = 0; mt < 4; ++mt)
#pragma unroll
            for (int nt = 0; nt < 4; ++nt)
                acc[mt][nt] = __builtin_amdgcn_mfma_f32_16x16x32_bf16(af[mt], bf[nt], acc[mt][nt], 0, 0, 0);
        __syncthreads();
    }

    if (MODE == 1) {
        // Wv row n = h*1024 + d*16 + r ; tile is 16-aligned so r == l16
#pragma unroll
        for (int nt = 0; nt < 4; ++nt) {
            int col = n0 + wn * 64 + nt * 16 + l16;
            int h   = col >> 10;
            int d   = (col >> 4) & 63;
            float bvv = bias[col];
#pragma unroll
            for (int mt = 0; mt < 4; ++mt) {
                int rowb = m0 + wm * 64 + mt * 16 + quad * 4;
#pragma unroll
                for (int rg = 0; rg < 4; ++rg) {
                    int token = rowb + rg;
                    float av = attn[(size_t)token * (HNUM * RNUM) + h * RNUM + l16];
                    float v  = (acc[mt][nt][rg] + bvv) * av;
                    v += __shfl_xor(v, 1);
                    v += __shfl_xor(v, 2);
                    v += __shfl_xor(v, 4);
                    v += __shfl_xor(v, 8);
                    if (l16 == 0) {
                        // reference's transpose(0,2,1,3).reshape scramble:
                        // row g = b*2048 + h*256 + s//8 ; col j = (s%8)*64 + d
                        int g = (token >> 11) * 2048 + h * 256 + ((token & 2047) >> 3);
                        int j = ((token & 7) << 6) + d;
                        outH[(size_t)g * EDIM + j] = f2b(v * 0.125f);
                    }
                }
            }
        }
    } else {
#pragma unroll
        for (int mt = 0; mt < 4; ++mt)
#pragma unroll
            for (int nt = 0; nt < 4; ++nt) {
                int col = n0 + wn * 64 + nt * 16 + l16;
                float bb = bias[col];
#pragma unroll
                for (int rg = 0; rg < 4; ++rg) {
                    int row = m0 + wm * 64 + mt * 16 + quad * 4 + rg;
                    float v = acc[mt][nt][rg] + bb;
                    if (MODE == 0) outF[(size_t)row * EDIM + col] = v * 0.125f;
                    else           outF[(size_t)row * EDIM + col] = v;
                }
            }
    }
}

// per (token, head): z_r = -0.5*mean_d(((q-k)/w)^2), softmax over 16 rules
__global__ __launch_bounds__(256)
void rules_softmax(const float* __restrict__ q,
                   const float* __restrict__ rk,
                   const float* __restrict__ rw,
                   float* __restrict__ attn)
{
    __shared__ float rkf[RNUM * DDIM];
    __shared__ float iw2[RNUM * DDIM];
    const int h   = blockIdx.y;
    const int tid = threadIdx.x;
#pragma unroll
    for (int i = 0; i < 4; ++i) {
        int j = tid + i * 256;
        rkf[j] = rk[h * (RNUM * DDIM) + j];
        float iw = 1.0f / rw[h * (RNUM * DDIM) + j];
        iw2[j] = iw * iw;
    }
    __syncthreads();

    const int token = blockIdx.x * 256 + tid;
    const float4* qb = (const float4*)(q + (size_t)token * EDIM + h * DDIM);
    float z[RNUM];
#pragma unroll
    for (int r = 0; r < RNUM; ++r) z[r] = 0.f;
#pragma unroll
    for (int d4 = 0; d4 < DDIM / 4; ++d4) {
        float4 qv = qb[d4];
        float qs[4] = {qv.x, qv.y, qv.z, qv.w};
#pragma unroll
        for (int jj = 0; jj < 4; ++jj) {
            int d = d4 * 4 + jj;
#pragma unroll
            for (int r = 0; r < RNUM; ++r) {
                float t = qs[jj] - rkf[r * DDIM + d];
                z[r] += t * t * iw2[r * DDIM + d];
            }
        }
    }
    float mx = -1e30f;
#pragma unroll
    for (int r = 0; r < RNUM; ++r) {
        z[r] *= (-0.5f / 64.f);
        mx = fmaxf(mx, z[r]);
    }
    float s = 0.f;
#pragma unroll
    for (int r = 0; r < RNUM; ++r) { z[r] = __expf(z[r] - mx); s += z[r]; }
    float inv = 1.0f / s;
    float* ap = attn + (size_t)token * (HNUM * RNUM) + h * RNUM;
#pragma unroll
    for (int r = 0; r < RNUM; ++r) ap[r] = z[r] * inv;
}

extern "C" void kernel_launch(void* const* d_in, const int* in_sizes, int n_in,
                              void* d_out, int out_size, void* d_ws, size_t ws_size,
                              hipStream_t stream) {
    const float* query = (const float*)d_in[0];
    // d_in[1] = key (unused by the reference)
    const float* value = (const float*)d_in[2];
    const float* Wq = (const float*)d_in[3];
    const float* bq = (const float*)d_in[4];
    const float* Wv = (const float*)d_in[5];
    const float* bv = (const float*)d_in[6];
    const float* Wo = (const float*)d_in[7];
    const float* bo = (const float*)d_in[8];
    const float* rk = (const float*)d_in[9];
    const float* rw = (const float*)d_in[10];

    char* ws = (char*)d_ws;
    // bf16 copies
    unsigned short* qbf  = (unsigned short*)(ws);                       //  8 MiB: query bf16 (8192x512)
    unsigned short* vbf  = (unsigned short*)(ws + (size_t)( 8 << 20));  //  8 MiB: value bf16
    unsigned short* Wqb  = (unsigned short*)(ws + (size_t)(16 << 20));  // 0.5 MiB
    unsigned short* Wvb  = (unsigned short*)(ws + (size_t)(17 << 20));  //  8 MiB
    unsigned short* Wob  = (unsigned short*)(ws + (size_t)(25 << 20));  // 0.5 MiB
    unsigned short* out1 = (unsigned short*)(ws + (size_t)(26 << 20));  //  8 MiB: scrambled bf16
    float* qf            = (float*)(ws + (size_t)(34 << 20));           // 16 MiB: q fp32 (8192x512)
    float* attn          = (float*)(ws + (size_t)(50 << 20));           //  4 MiB: attn fp32 (8192x128)

    dim3 blk(256);
    // 0) fp32 -> bf16 conversions (query, value, Wq, Wv, Wo)
    cvt5<<<dim3(2048, 5), blk, 0, stream>>>(query, value, Wv, Wq, Wo,
                                            qbf, vbf, Wvb, Wqb, Wob,
                                            TOKENS * EDIM, TOKENS * EDIM, EDIM * RNUM * EDIM,
                                            EDIM * EDIM, EDIM * EDIM);
    // 1) q = (query @ Wq^T + bq) * D^-0.5   (fp32 out)
    gemm_bt<0><<<dim3(TOKENS / 128, EDIM / 128), blk, 0, stream>>>(qbf, Wqb, bq, qf, nullptr, nullptr);
    // 2) fuzzy rule attention weights
    rules_softmax<<<dim3(TOKENS / 256, HNUM), blk, 0, stream>>>(qf, rk, rw, attn);
    // 3) V-GEMM fused with rule contraction -> scrambled out1 (bf16)
    gemm_bt<1><<<dim3(TOKENS / 128, (EDIM * RNUM) / 128), blk, 0, stream>>>(vbf, Wvb, bv, nullptr, out1, attn);
    // 4) final projection -> d_out (fp32)
    gemm_bt<2><<<dim3(TOKENS / 128, EDIM / 128), blk, 0, stream>>>(out1, Wob, bo, (float*)d_out, nullptr, nullptr);
}

// Round 3
// 241.737 us; speedup vs baseline: 1.1345x; 1.1345x over previous
//
#include <hip/hip_runtime.h>
#include <stdint.h>

#define TOKENS 8192
#define EDIM 512
#define HNUM 8
#define RNUM 16
#define DDIM 64
#define KDIM 512

typedef short v8s __attribute__((ext_vector_type(8)));
typedef float v4f __attribute__((ext_vector_type(4)));

__device__ inline float b2f(unsigned short u) {
    union { unsigned int i; float f; } c; c.i = ((unsigned int)u) << 16; return c.f;
}
__device__ inline unsigned short f2b(float f) {
    union { float f; unsigned int i; } c; c.f = f;
    unsigned int i = c.i + 0x7fffu + ((c.i >> 16) & 1u);
    return (unsigned short)(i >> 16);
}

// async global->LDS, 16B per lane; LDS dest = wave-uniform base + lane*16
#define GLD16(dst, src) \
    __builtin_amdgcn_global_load_lds((__attribute__((address_space(1))) void*)(src), \
                                     (__attribute__((address_space(3))) void*)(dst), 16, 0, 0)

// ---- fp32 -> bf16 convert, 5 segments in one launch (blockIdx.y picks) ----
__global__ __launch_bounds__(256)
void cvt5(const float* __restrict__ s0, const float* __restrict__ s1,
          const float* __restrict__ s2, const float* __restrict__ s3,
          const float* __restrict__ s4,
          unsigned short* __restrict__ d0, unsigned short* __restrict__ d1,
          unsigned short* __restrict__ d2, unsigned short* __restrict__ d3,
          unsigned short* __restrict__ d4,
          int n0, int n1, int n2, int n3, int n4)
{
    const float* s; unsigned short* d; int n;
    switch (blockIdx.y) {
        case 0: s = s0; d = d0; n = n0; break;
        case 1: s = s1; d = d1; n = n1; break;
        case 2: s = s2; d = d2; n = n2; break;
        case 3: s = s3; d = d3; n = n3; break;
        default: s = s4; d = d4; n = n4; break;
    }
    size_t base = (size_t)blockIdx.x * 2048 + (size_t)threadIdx.x * 8;
    if (base >= (size_t)n) return;
    const float4* sp = (const float4*)(s + base);
    float4 f0 = sp[0], f1 = sp[1];
    v8s o;
    o[0] = (short)f2b(f0.x); o[1] = (short)f2b(f0.y);
    o[2] = (short)f2b(f0.z); o[3] = (short)f2b(f0.w);
    o[4] = (short)f2b(f1.x); o[5] = (short)f2b(f1.y);
    o[6] = (short)f2b(f1.z); o[7] = (short)f2b(f1.w);
    *(v8s*)(d + base) = o;
}

// C[m,n] = sum_k A[m,k]*B[n,k]   (A: M x 512 bf16 row-major, B: N x 512 bf16 row-major)
// MODE 0: outH[m*512+n] = bf16((C + bias[n]) * 0.125)    (Q projection, bf16 out)
// MODE 1: TRANSPOSED V-GEMM: m-axis = Wv rows (h*1024+d*16+r), n-axis = tokens.
//         Rule contraction over r = quad*4+reg (in-register + 2 shfl), then
//         LDS-staged coalesced store of scrambled out1.
// MODE 2: outF[m*512+n] = C + bias[n]                    (O projection, fp32 out)
template <int MODE>
__global__ __launch_bounds__(256, 2)
void gemm_bt(const unsigned short* __restrict__ A,
             const unsigned short* __restrict__ B,
             const float* __restrict__ bias,
             float* __restrict__ outF,
             unsigned short* __restrict__ outH,
             const float* __restrict__ attn)
{
    __shared__ unsigned short As[128 * 32];
    __shared__ unsigned short Bs[128 * 32];
    __shared__ unsigned short Os[128 * 8];   // MODE 1 result stage

    const int tid  = threadIdx.x;
    const int w    = tid >> 6;
    const int lane = tid & 63;
    const int quad = lane >> 4;
    const int l16  = lane & 15;
    const int wm   = w >> 1, wn = w & 1;
    const int m0   = blockIdx.x * 128;
    const int n0   = blockIdx.y * 128;

    v4f acc[4][4];
#pragma unroll
    for (int i = 0; i < 4; ++i)
#pragma unroll
        for (int j = 0; j < 4; ++j)
            acc[i][j] = (v4f){0.f, 0.f, 0.f, 0.f};

    for (int kt = 0; kt < KDIM / 32; ++kt) {
        // ---- stage A,B tiles (128x32 bf16 each) via global_load_lds ----
#pragma unroll
        for (int p = 0; p < 2; ++p) {
            int cb = w * 128 + p * 64;     // wave-uniform chunk base (16B chunks)
            int c  = cb + lane;            // this lane's chunk
            const unsigned short* sa = A + (size_t)(m0 + (c >> 2)) * KDIM + kt * 32 + (c & 3) * 8;
            GLD16(&As[cb * 8], sa);
            const unsigned short* sb = B + (size_t)(n0 + (c >> 2)) * KDIM + kt * 32 + (c & 3) * 8;
            GLD16(&Bs[cb * 8], sb);
        }
        __syncthreads();

        // ---- fragments + 16 MFMAs ----
        v8s af[4], bf[4];
#pragma unroll
        for (int mt = 0; mt < 4; ++mt)
            af[mt] = *(const v8s*)&As[(wm * 64 + mt * 16 + l16) * 32 + quad * 8];
#pragma unroll
        for (int nt = 0; nt < 4; ++nt)
            bf[nt] = *(const v8s*)&Bs[(wn * 64 + nt * 16 + l16) * 32 + quad * 8];
#pragma unroll
        for (int mt = 0; mt < 4; ++mt)
#pragma unroll
            for (int nt = 0; nt < 4; ++nt)
                acc[mt][nt] = __builtin_amdgcn_mfma_f32_16x16x32_bf16(af[mt], bf[nt], acc[mt][nt], 0, 0, 0);
        __syncthreads();
    }

    if (MODE == 1) {
        const int h  = m0 >> 10;          // head (uniform per block)
        const int d0 = (m0 >> 4) & 63;    // first d of this block's 8 d values (8-aligned)
        // bias float4 per mt: bias[m], m = m0+wm*64+mt*16+quad*4 .. +3  (r = quad*4+rg)
        float4 bias4[4];
#pragma unroll
        for (int mt = 0; mt < 4; ++mt)
            bias4[mt] = *(const float4*)&bias[m0 + wm * 64 + mt * 16 + quad * 4];
#pragma unroll
        for (int nt = 0; nt < 4; ++nt) {
            int token = n0 + wn * 64 + nt * 16 + l16;
            float4 av = *(const float4*)&attn[(size_t)token * (HNUM * RNUM) + h * RNUM + quad * 4];
#pragma unroll
            for (int mt = 0; mt < 4; ++mt) {
                v4f a = acc[mt][nt];
                float val = (a[0] + bias4[mt].x) * av.x
                          + (a[1] + bias4[mt].y) * av.y
                          + (a[2] + bias4[mt].z) * av.z
                          + (a[3] + bias4[mt].w) * av.w;
                val += __shfl_xor(val, 16);
                val += __shfl_xor(val, 32);
                if (quad == 0)
                    Os[(wn * 64 + nt * 16 + l16) * 8 + (wm * 4 + mt)] = f2b(val * 0.125f);
            }
        }
        __syncthreads();
        if (tid < 128) {
            int sg = n0 + tid;            // global token
            int g  = (sg >> 11) * 2048 + h * 256 + ((sg & 2047) >> 3);
            int j  = (sg & 7) * 64 + d0;
            *(v8s*)&outH[(size_t)g * EDIM + j] = *(const v8s*)&Os[tid * 8];
        }
    } else {
#pragma unroll
        for (int mt = 0; mt < 4; ++mt)
#pragma unroll
            for (int nt = 0; nt < 4; ++nt) {
                int col = n0 + wn * 64 + nt * 16 + l16;
                float bb = bias[col];
#pragma unroll
                for (int rg = 0; rg < 4; ++rg) {
                    int row = m0 + wm * 64 + mt * 16 + quad * 4 + rg;
                    float v = acc[mt][nt][rg] + bb;
                    if (MODE == 0) outH[(size_t)row * EDIM + col] = f2b(v * 0.125f);
                    else           outF[(size_t)row * EDIM + col] = v;
                }
            }
    }
}

// per (token, head): z_r = -0.5*mean_d(((q-k)/w)^2), softmax over 16 rules.
// grid (TOKENS/16, HNUM), block 256 = 16 tokens x 16 rules.
#define RST 72   // padded LDS row stride (floats), 16B-aligned, conflict-free
__global__ __launch_bounds__(256)
void rules_softmax(const unsigned short* __restrict__ q,  // bf16 (8192 x 512)
                   const float* __restrict__ rk,
                   const float* __restrict__ rw,
                   float* __restrict__ attn)
{
    __shared__ float ql[16 * RST];
    __shared__ float rkl[16 * RST];
    __shared__ float iwl[16 * RST];
    const int h   = blockIdx.y;
    const int t0  = blockIdx.x * 16;
    const int tid = threadIdx.x;

    // stage rules (coalesced)
#pragma unroll
    for (int i = 0; i < 4; ++i) {
        int jj = tid + i * 256;
        int r = jj >> 6, d = jj & 63;
        rkl[r * RST + d] = rk[h * (RNUM * DDIM) + jj];
        float wv = rw[h * (RNUM * DDIM) + jj];
        iwl[r * RST + d] = 1.0f / (wv * wv);
    }
    // stage q slice: 16 tokens x 64 bf16, 8B per thread (coalesced)
    {
        int jj = tid * 4;                 // element index in 16x64
        int row = jj >> 6, d = jj & 63;
        const unsigned short* src = q + (size_t)(t0 + row) * EDIM + h * DDIM + d;
        unsigned short u0 = src[0], u1 = src[1], u2 = src[2], u3 = src[3];
        ql[row * RST + d + 0] = b2f(u0);
        ql[row * RST + d + 1] = b2f(u1);
        ql[row * RST + d + 2] = b2f(u2);
        ql[row * RST + d + 3] = b2f(u3);
    }
    __syncthreads();

    const int tl = tid >> 4;   // token within the wave group (= lane>>4 in-wave)
    const int r  = tid & 15;   // rule (= lane&15)
    const float* qrow = &ql[tl * RST];
    const float* krow = &rkl[r * RST];
    const float* wrow = &iwl[r * RST];
    float z = 0.f;
#pragma unroll
    for (int d4 = 0; d4 < 16; ++d4) {
        float4 qv = *(const float4*)&qrow[d4 * 4];
        float4 kv = *(const float4*)&krow[d4 * 4];
        float4 wv = *(const float4*)&wrow[d4 * 4];
        float a0 = qv.x - kv.x; z += a0 * a0 * wv.x;
        float a1 = qv.y - kv.y; z += a1 * a1 * wv.y;
        float a2 = qv.z - kv.z; z += a2 * a2 * wv.z;
        float a3 = qv.w - kv.w; z += a3 * a3 * wv.w;
    }
    z *= (-0.5f / 64.f);
    // softmax over the 16 rule lanes
    float mx = z;
#pragma unroll
    for (int s = 1; s < 16; s <<= 1) mx = fmaxf(mx, __shfl_xor(mx, s));
    float e = __expf(z - mx);
    float sum = e;
#pragma unroll
    for (int s = 1; s < 16; s <<= 1) sum += __shfl_xor(sum, s);
    attn[(size_t)(t0 + tl) * (HNUM * RNUM) + h * RNUM + r] = e / sum;
}

extern "C" void kernel_launch(void* const* d_in, const int* in_sizes, int n_in,
                              void* d_out, int out_size, void* d_ws, size_t ws_size,
                              hipStream_t stream) {
    const float* query = (const float*)d_in[0];
    // d_in[1] = key (unused by the reference)
    const float* value = (const float*)d_in[2];
    const float* Wq = (const float*)d_in[3];
    const float* bq = (const float*)d_in[4];
    const float* Wv = (const float*)d_in[5];
    const float* bv = (const float*)d_in[6];
    const float* Wo = (const float*)d_in[7];
    const float* bo = (const float*)d_in[8];
    const float* rk = (const float*)d_in[9];
    const float* rw = (const float*)d_in[10];

    char* ws = (char*)d_ws;
    unsigned short* qbf  = (unsigned short*)(ws);                       //  8 MiB: query bf16
    unsigned short* vbf  = (unsigned short*)(ws + (size_t)( 8 << 20));  //  8 MiB: value bf16
    unsigned short* Wqb  = (unsigned short*)(ws + (size_t)(16 << 20));  // 0.5 MiB
    unsigned short* Wvb  = (unsigned short*)(ws + (size_t)(17 << 20));  //  8 MiB
    unsigned short* Wob  = (unsigned short*)(ws + (size_t)(25 << 20));  // 0.5 MiB
    unsigned short* out1 = (unsigned short*)(ws + (size_t)(26 << 20));  //  8 MiB: scrambled bf16
    unsigned short* qf   = (unsigned short*)(ws + (size_t)(34 << 20));  //  8 MiB: q bf16 (8192x512)
    float* attn          = (float*)(ws + (size_t)(42 << 20));           //  4 MiB: attn fp32

    dim3 blk(256);
    // 0) fp32 -> bf16 conversions
    cvt5<<<dim3(2048, 5), blk, 0, stream>>>(query, value, Wv, Wq, Wo,
                                            qbf, vbf, Wvb, Wqb, Wob,
                                            TOKENS * EDIM, TOKENS * EDIM, EDIM * RNUM * EDIM,
                                            EDIM * EDIM, EDIM * EDIM);
    // 1) q = bf16((query @ Wq^T + bq) * D^-0.5)
    gemm_bt<0><<<dim3(TOKENS / 128, EDIM / 128), blk, 0, stream>>>(qbf, Wqb, bq, nullptr, qf, nullptr);
    // 2) fuzzy rule attention weights
    rules_softmax<<<dim3(TOKENS / 16, HNUM), blk, 0, stream>>>(qf, rk, rw, attn);
    // 3) transposed V-GEMM (A = Wv rows, B = tokens) + rule contraction -> scrambled out1
    gemm_bt<1><<<dim3((EDIM * RNUM) / 128, TOKENS / 128), blk, 0, stream>>>(Wvb, vbf, bv, nullptr, out1, attn);
    // 4) final projection -> d_out (fp32)
    gemm_bt<2><<<dim3(TOKENS / 128, EDIM / 128), blk, 0, stream>>>(out1, Wob, bo, (float*)d_out, nullptr, nullptr);
}

// Round 4
// 232.800 us; speedup vs baseline: 1.1781x; 1.0384x over previous
//
#include <hip/hip_runtime.h>
#include <stdint.h>

#define TOKENS 8192
#define EDIM 512
#define HNUM 8
#define RNUM 16
#define DDIM 64
#define KDIM 512

typedef short v8s __attribute__((ext_vector_type(8)));
typedef float v4f __attribute__((ext_vector_type(4)));

__device__ inline float b2f(unsigned short u) {
    union { unsigned int i; float f; } c; c.i = ((unsigned int)u) << 16; return c.f;
}
__device__ inline unsigned short f2b(float f) {
    union { float f; unsigned int i; } c; c.f = f;
    unsigned int i = c.i + 0x7fffu + ((c.i >> 16) & 1u);
    return (unsigned short)(i >> 16);
}

// async global->LDS, 16B per lane; LDS dest = wave-uniform base + lane*16
#define GLD16(dst, src) \
    __builtin_amdgcn_global_load_lds((__attribute__((address_space(1))) void*)(src), \
                                     (__attribute__((address_space(3))) void*)(dst), 16, 0, 0)

// ---- fp32 -> bf16 convert, 5 segments in one launch (blockIdx.y picks) ----
__global__ __launch_bounds__(256)
void cvt5(const float* __restrict__ s0, const float* __restrict__ s1,
          const float* __restrict__ s2, const float* __restrict__ s3,
          const float* __restrict__ s4,
          unsigned short* __restrict__ d0, unsigned short* __restrict__ d1,
          unsigned short* __restrict__ d2, unsigned short* __restrict__ d3,
          unsigned short* __restrict__ d4,
          int n0, int n1, int n2, int n3, int n4)
{
    const float* s; unsigned short* d; int n;
    switch (blockIdx.y) {
        case 0: s = s0; d = d0; n = n0; break;
        case 1: s = s1; d = d1; n = n1; break;
        case 2: s = s2; d = d2; n = n2; break;
        case 3: s = s3; d = d3; n = n3; break;
        default: s = s4; d = d4; n = n4; break;
    }
    size_t base = (size_t)blockIdx.x * 2048 + (size_t)threadIdx.x * 8;
    if (base >= (size_t)n) return;
    const float4* sp = (const float4*)(s + base);
    float4 f0 = sp[0], f1 = sp[1];
    v8s o;
    o[0] = (short)f2b(f0.x); o[1] = (short)f2b(f0.y);
    o[2] = (short)f2b(f0.z); o[3] = (short)f2b(f0.w);
    o[4] = (short)f2b(f1.x); o[5] = (short)f2b(f1.y);
    o[6] = (short)f2b(f1.z); o[7] = (short)f2b(f1.w);
    *(v8s*)(d + base) = o;
}

// ---- small-GEMM path: 64x64 tiles, 1024 blocks -> 4 blocks/CU ----
// C[m,n] = sum_k A[m,k]*B[n,k]; K = 512.
// MODE 0: outH = bf16((C + bias[n]) * 0.125)   (Q projection)
// MODE 2: outF = C + bias[n]                   (O projection)
template <int MODE>
__global__ __launch_bounds__(256, 4)
void gemm64(const unsigned short* __restrict__ A,
            const unsigned short* __restrict__ B,
            const float* __restrict__ bias,
            float* __restrict__ outF,
            unsigned short* __restrict__ outH)
{
    __shared__ unsigned short As[64 * 32];
    __shared__ unsigned short Bs[64 * 32];

    const int tid  = threadIdx.x;
    const int w    = tid >> 6;
    const int lane = tid & 63;
    const int quad = lane >> 4;
    const int l16  = lane & 15;
    const int wm   = w >> 1, wn = w & 1;
    const int m0   = blockIdx.x * 64;
    const int n0   = blockIdx.y * 64;

    v4f acc[2][2];
#pragma unroll
    for (int i = 0; i < 2; ++i)
#pragma unroll
        for (int j = 0; j < 2; ++j)
            acc[i][j] = (v4f){0.f, 0.f, 0.f, 0.f};

    for (int kt = 0; kt < KDIM / 32; ++kt) {
        // 256 chunks (16B) per 64x32 tile; each thread stages 1 chunk of A + 1 of B
        int c = w * 64 + lane;
        const unsigned short* sa = A + (size_t)(m0 + (c >> 2)) * KDIM + kt * 32 + (c & 3) * 8;
        GLD16(&As[w * 512], sa);
        const unsigned short* sb = B + (size_t)(n0 + (c >> 2)) * KDIM + kt * 32 + (c & 3) * 8;
        GLD16(&Bs[w * 512], sb);
        __syncthreads();

        v8s af[2], bf[2];
#pragma unroll
        for (int mt = 0; mt < 2; ++mt)
            af[mt] = *(const v8s*)&As[(wm * 32 + mt * 16 + l16) * 32 + quad * 8];
#pragma unroll
        for (int nt = 0; nt < 2; ++nt)
            bf[nt] = *(const v8s*)&Bs[(wn * 32 + nt * 16 + l16) * 32 + quad * 8];
#pragma unroll
        for (int mt = 0; mt < 2; ++mt)
#pragma unroll
            for (int nt = 0; nt < 2; ++nt)
                acc[mt][nt] = __builtin_amdgcn_mfma_f32_16x16x32_bf16(af[mt], bf[nt], acc[mt][nt], 0, 0, 0);
        __syncthreads();
    }

#pragma unroll
    for (int mt = 0; mt < 2; ++mt)
#pragma unroll
        for (int nt = 0; nt < 2; ++nt) {
            int col = n0 + wn * 32 + nt * 16 + l16;
            float bb = bias[col];
#pragma unroll
            for (int rg = 0; rg < 4; ++rg) {
                int row = m0 + wm * 32 + mt * 16 + quad * 4 + rg;
                float v = acc[mt][nt][rg] + bb;
                if (MODE == 0) outH[(size_t)row * EDIM + col] = f2b(v * 0.125f);
                else           outF[(size_t)row * EDIM + col] = v;
            }
        }
}

// ---- V-GEMM: 128x128 tiles, TRANSPOSED (m = Wv rows h*1024+d*16+r, n = tokens) ----
// Rule contraction over r = quad*4+reg (in-register + 2 shfl), LDS-staged
// coalesced store of scrambled out1.
__global__ __launch_bounds__(256, 2)
void gemm_v(const unsigned short* __restrict__ A,
            const unsigned short* __restrict__ B,
            const float* __restrict__ bias,
            unsigned short* __restrict__ outH,
            const float* __restrict__ attn)
{
    __shared__ unsigned short As[128 * 32];
    __shared__ unsigned short Bs[128 * 32];
    __shared__ unsigned short Os[128 * 8];

    const int tid  = threadIdx.x;
    const int w    = tid >> 6;
    const int lane = tid & 63;
    const int quad = lane >> 4;
    const int l16  = lane & 15;
    const int wm   = w >> 1, wn = w & 1;
    const int m0   = blockIdx.x * 128;
    const int n0   = blockIdx.y * 128;

    v4f acc[4][4];
#pragma unroll
    for (int i = 0; i < 4; ++i)
#pragma unroll
        for (int j = 0; j < 4; ++j)
            acc[i][j] = (v4f){0.f, 0.f, 0.f, 0.f};

    for (int kt = 0; kt < KDIM / 32; ++kt) {
#pragma unroll
        for (int p = 0; p < 2; ++p) {
            int cb = w * 128 + p * 64;
            int c  = cb + lane;
            const unsigned short* sa = A + (size_t)(m0 + (c >> 2)) * KDIM + kt * 32 + (c & 3) * 8;
            GLD16(&As[cb * 8], sa);
            const unsigned short* sb = B + (size_t)(n0 + (c >> 2)) * KDIM + kt * 32 + (c & 3) * 8;
            GLD16(&Bs[cb * 8], sb);
        }
        __syncthreads();

        v8s af[4], bf[4];
#pragma unroll
        for (int mt = 0; mt < 4; ++mt)
            af[mt] = *(const v8s*)&As[(wm * 64 + mt * 16 + l16) * 32 + quad * 8];
#pragma unroll
        for (int nt = 0; nt < 4; ++nt)
            bf[nt] = *(const v8s*)&Bs[(wn * 64 + nt * 16 + l16) * 32 + quad * 8];
#pragma unroll
        for (int mt = 0; mt < 4; ++mt)
#pragma unroll
            for (int nt = 0; nt < 4; ++nt)
                acc[mt][nt] = __builtin_amdgcn_mfma_f32_16x16x32_bf16(af[mt], bf[nt], acc[mt][nt], 0, 0, 0);
        __syncthreads();
    }

    const int h  = m0 >> 10;          // head (uniform per block)
    const int d0 = (m0 >> 4) & 63;    // first of this block's 8 d values
    float4 bias4[4];
#pragma unroll
    for (int mt = 0; mt < 4; ++mt)
        bias4[mt] = *(const float4*)&bias[m0 + wm * 64 + mt * 16 + quad * 4];
#pragma unroll
    for (int nt = 0; nt < 4; ++nt) {
        int token = n0 + wn * 64 + nt * 16 + l16;
        float4 av = *(const float4*)&attn[(size_t)token * (HNUM * RNUM) + h * RNUM + quad * 4];
#pragma unroll
        for (int mt = 0; mt < 4; ++mt) {
            v4f a = acc[mt][nt];
            float val = (a[0] + bias4[mt].x) * av.x
                      + (a[1] + bias4[mt].y) * av.y
                      + (a[2] + bias4[mt].z) * av.z
                      + (a[3] + bias4[mt].w) * av.w;
            val += __shfl_xor(val, 16);
            val += __shfl_xor(val, 32);
            if (quad == 0)
                Os[(wn * 64 + nt * 16 + l16) * 8 + (wm * 4 + mt)] = f2b(val * 0.125f);
        }
    }
    __syncthreads();
    if (tid < 128) {
        int sg = n0 + tid;            // global token
        int g  = (sg >> 11) * 2048 + h * 256 + ((sg & 2047) >> 3);
        int j  = (sg & 7) * 64 + d0;
        *(v8s*)&outH[(size_t)g * EDIM + j] = *(const v8s*)&Os[tid * 8];
    }
}

// per (token, head): z_r = -0.5*mean_d(((q-k)/w)^2), softmax over 16 rules.
// grid (TOKENS/16, HNUM), block 256 = 16 tokens x 16 rules.
#define RST 72   // padded LDS row stride (floats)
__global__ __launch_bounds__(256)
void rules_softmax(const unsigned short* __restrict__ q,  // bf16 (8192 x 512)
                   const float* __restrict__ rk,
                   const float* __restrict__ rw,
                   float* __restrict__ attn)
{
    __shared__ float ql[16 * RST];
    __shared__ float rkl[16 * RST];
    __shared__ float iwl[16 * RST];
    const int h   = blockIdx.y;
    const int t0  = blockIdx.x * 16;
    const int tid = threadIdx.x;

#pragma unroll
    for (int i = 0; i < 4; ++i) {
        int jj = tid + i * 256;
        int r = jj >> 6, d = jj & 63;
        rkl[r * RST + d] = rk[h * (RNUM * DDIM) + jj];
        float wv = rw[h * (RNUM * DDIM) + jj];
        iwl[r * RST + d] = 1.0f / (wv * wv);
    }
    {
        int jj = tid * 4;
        int row = jj >> 6, d = jj & 63;
        const unsigned short* src = q + (size_t)(t0 + row) * EDIM + h * DDIM + d;
        unsigned short u0 = src[0], u1 = src[1], u2 = src[2], u3 = src[3];
        ql[row * RST + d + 0] = b2f(u0);
        ql[row * RST + d + 1] = b2f(u1);
        ql[row * RST + d + 2] = b2f(u2);
        ql[row * RST + d + 3] = b2f(u3);
    }
    __syncthreads();

    const int tl = tid >> 4;
    const int r  = tid & 15;
    const float* qrow = &ql[tl * RST];
    const float* krow = &rkl[r * RST];
    const float* wrow = &iwl[r * RST];
    float z = 0.f;
#pragma unroll
    for (int d4 = 0; d4 < 16; ++d4) {
        float4 qv = *(const float4*)&qrow[d4 * 4];
        float4 kv = *(const float4*)&krow[d4 * 4];
        float4 wv = *(const float4*)&wrow[d4 * 4];
        float a0 = qv.x - kv.x; z += a0 * a0 * wv.x;
        float a1 = qv.y - kv.y; z += a1 * a1 * wv.y;
        float a2 = qv.z - kv.z; z += a2 * a2 * wv.z;
        float a3 = qv.w - kv.w; z += a3 * a3 * wv.w;
    }
    z *= (-0.5f / 64.f);
    float mx = z;
#pragma unroll
    for (int s = 1; s < 16; s <<= 1) mx = fmaxf(mx, __shfl_xor(mx, s));
    float e = __expf(z - mx);
    float sum = e;
#pragma unroll
    for (int s = 1; s < 16; s <<= 1) sum += __shfl_xor(sum, s);
    attn[(size_t)(t0 + tl) * (HNUM * RNUM) + h * RNUM + r] = e / sum;
}

extern "C" void kernel_launch(void* const* d_in, const int* in_sizes, int n_in,
                              void* d_out, int out_size, void* d_ws, size_t ws_size,
                              hipStream_t stream) {
    const float* query = (const float*)d_in[0];
    // d_in[1] = key (unused by the reference)
    const float* value = (const float*)d_in[2];
    const float* Wq = (const float*)d_in[3];
    const float* bq = (const float*)d_in[4];
    const float* Wv = (const float*)d_in[5];
    const float* bv = (const float*)d_in[6];
    const float* Wo = (const float*)d_in[7];
    const float* bo = (const float*)d_in[8];
    const float* rk = (const float*)d_in[9];
    const float* rw = (const float*)d_in[10];

    char* ws = (char*)d_ws;
    unsigned short* qbf  = (unsigned short*)(ws);                       //  8 MiB: query bf16
    unsigned short* vbf  = (unsigned short*)(ws + (size_t)( 8 << 20));  //  8 MiB: value bf16
    unsigned short* Wqb  = (unsigned short*)(ws + (size_t)(16 << 20));  // 0.5 MiB
    unsigned short* Wvb  = (unsigned short*)(ws + (size_t)(17 << 20));  //  8 MiB
    unsigned short* Wob  = (unsigned short*)(ws + (size_t)(25 << 20));  // 0.5 MiB
    unsigned short* out1 = (unsigned short*)(ws + (size_t)(26 << 20));  //  8 MiB: scrambled bf16
    unsigned short* qf   = (unsigned short*)(ws + (size_t)(34 << 20));  //  8 MiB: q bf16
    float* attn          = (float*)(ws + (size_t)(42 << 20));           //  4 MiB: attn fp32

    dim3 blk(256);
    // 0) fp32 -> bf16 conversions
    cvt5<<<dim3(2048, 5), blk, 0, stream>>>(query, value, Wv, Wq, Wo,
                                            qbf, vbf, Wvb, Wqb, Wob,
                                            TOKENS * EDIM, TOKENS * EDIM, EDIM * RNUM * EDIM,
                                            EDIM * EDIM, EDIM * EDIM);
    // 1) q = bf16((query @ Wq^T + bq) * D^-0.5)   [64x64 tiles, 1024 blocks]
    gemm64<0><<<dim3(TOKENS / 64, EDIM / 64), blk, 0, stream>>>(qbf, Wqb, bq, nullptr, qf);
    // 2) fuzzy rule attention weights
    rules_softmax<<<dim3(TOKENS / 16, HNUM), blk, 0, stream>>>(qf, rk, rw, attn);
    // 3) transposed V-GEMM + rule contraction -> scrambled out1
    gemm_v<<<dim3((EDIM * RNUM) / 128, TOKENS / 128), blk, 0, stream>>>(Wvb, vbf, bv, out1, attn);
    // 4) final projection -> d_out (fp32)  [64x64 tiles, 1024 blocks]
    gemm64<2><<<dim3(TOKENS / 64, EDIM / 64), blk, 0, stream>>>(out1, Wob, bo, (float*)d_out, nullptr);
}